// Round 10
// baseline (317.115 us; speedup 1.0000x reference)
//
#include <hip/hip_runtime.h>
#include <hip/hip_bf16.h>

// MHA forward: B=2, N=4096, E=768, H=8, D=96. All-fp16 datapath (f32 accum).
// R10: deferred-PV (T15) — acc = acc*sc(t-1) + V(t-1)P(t-1) overlaps softmax(t)
// with PV MFMAs; 1 barrier/tile (vmcnt(0)-certify BEFORE barrier, issue after);
// K dbuf + V dbuf; log2-domain softmax, defer-max THR=12, cvt_pkrtz P-pack.

typedef unsigned short u16;
typedef unsigned long long u64;
typedef __attribute__((ext_vector_type(4))) float f32x4;
typedef __attribute__((ext_vector_type(8))) _Float16 h16x8;
typedef __attribute__((ext_vector_type(2))) __fp16 fp16x2;   // cvt_pkrtz native type
typedef __attribute__((ext_vector_type(8))) u16 u16x8;

#define DEVI static __device__ __forceinline__

// global->LDS DMA, 16B/lane; LDS dest = wave-uniform base + lane*16 (m104)
#define GLD16(gp, lp)                                                          \
  __builtin_amdgcn_global_load_lds(                                            \
      (const __attribute__((address_space(1))) void*)(gp),                     \
      (__attribute__((address_space(3))) void*)(lp), 16, 0, 0)
#define VM_WAIT4() asm volatile("s_waitcnt vmcnt(4)" ::: "memory")
#define VM_WAIT0() asm volatile("s_waitcnt vmcnt(0)" ::: "memory")
#define BARRAW()   asm volatile("s_barrier" ::: "memory")

DEVI u16 f2h(float f) {
  _Float16 h = (_Float16)f;           // v_cvt_f16_f32, RNE
  return __builtin_bit_cast(u16, h);
}

DEVI unsigned pkrtz(float a, float b) {
  fp16x2 h = __builtin_amdgcn_cvt_pkrtz(a, b);   // v_cvt_pkrtz_f16_f32
  return __builtin_bit_cast(unsigned, h);
}

DEVI float exp2fast(float x) {
#if __has_builtin(__builtin_amdgcn_exp2f)
  return __builtin_amdgcn_exp2f(x);
#else
  return __expf(x * 0.6931471805599453f);
#endif
}

DEVI f32x4 mfma16(u16x8 a, u16x8 b, f32x4 c) {
  return __builtin_amdgcn_mfma_f32_16x16x32_f16(
      __builtin_bit_cast(h16x8, a), __builtin_bit_cast(h16x8, b), c, 0, 0, 0);
}

// ---------------- cast x (f32 -> fp16), 8 elems/thread ----------------
__global__ void k_cast(const float* __restrict__ x, u16* __restrict__ xh, int n8) {
  int i = blockIdx.x * blockDim.x + threadIdx.x;
  if (i >= n8) return;
  const f32x4* p = (const f32x4*)x + (size_t)i * 2;
  f32x4 a = p[0], b = p[1];
  u16x8 o;
  #pragma unroll
  for (int u = 0; u < 4; ++u) { o[u] = f2h(a[u]); o[4 + u] = f2h(b[u]); }
  *((u16x8*)xh + i) = o;
}

// ------------- weight transpose+cast: wT[mat][n][k] = W[k][n], f32->fp16 -------------
__global__ void k_wt(const float* __restrict__ Wq, const float* __restrict__ Wk,
                     const float* __restrict__ Wv, const float* __restrict__ Wo,
                     u16* __restrict__ wT) {
  __shared__ __align__(16) float T[64 * 68];
  int bid = blockIdx.x;
  int mat = bid / 144, tt = bid % 144;
  int tr = tt / 12, tc = tt % 12;            // tr: k-tile, tc: n-tile
  const float* W = (mat == 0) ? Wq : (mat == 1) ? Wk : (mat == 2) ? Wv : Wo;
  int k0 = tr * 64, n0 = tc * 64;
  int t = threadIdx.x;
  #pragma unroll
  for (int ii = 0; ii < 4; ++ii) {
    int i = t + 256 * ii, r = i >> 4, c4 = i & 15;
    f32x4 v = *(const f32x4*)(W + (size_t)(k0 + r) * 768 + n0 + c4 * 4);
    *(f32x4*)(&T[r * 68 + c4 * 4]) = v;
  }
  __syncthreads();
  #pragma unroll
  for (int ii = 0; ii < 2; ++ii) {
    int i = t + 256 * ii, nn = i & 63, kc8 = i >> 6;
    u16x8 o;
    #pragma unroll
    for (int u = 0; u < 8; ++u) o[u] = f2h(T[(kc8 * 8 + u) * 68 + nn]);
    *(u16x8*)(wT + (size_t)mat * 589824 + (size_t)(n0 + nn) * 768 + k0 + kc8 * 8) = o;
  }
}

// ------------- V [BH][N][D] -> Vt [BH][D][N] (u16 passthrough) -------------
__global__ void k_vt(const u16* __restrict__ V, u16* __restrict__ Vt) {
  __shared__ __align__(16) u16 L[64 * 104];
  int bid = blockIdx.x, bh = bid >> 6, nb = bid & 63;
  int n0 = nb * 64, t = threadIdx.x;
  const u16* src = V + ((size_t)bh * 4096 + n0) * 96;
  #pragma unroll
  for (int ii = 0; ii < 3; ++ii) {
    int i = t + 256 * ii, r = i / 12, c8 = i % 12;
    *(u16x8*)(&L[r * 104 + c8 * 8]) = *(const u16x8*)(src + (size_t)i * 8);
  }
  __syncthreads();
  #pragma unroll
  for (int jj = 0; jj < 3; ++jj) {
    int d = (t & 31) + 32 * jj, c8 = t >> 5;
    u16x8 o;
    #pragma unroll
    for (int u = 0; u < 8; ++u) o[u] = L[(c8 * 8 + u) * 104 + d];
    *(u16x8*)(Vt + ((size_t)bh * 96 + d) * 4096 + n0 + c8 * 8) = o;
  }
}

// ------------- GEMM: 128x128 tile, BK=32, 4 waves, 2-phase pipelined DMA -------------
// MODE 0: QKV  A=xh[8192][768], BT=wT[2304][768] -> Qb/Kb/Vb fp16 [B,H,N,D] +bias
//         (Q outputs scaled by log2e for log2-domain softmax)
// MODE 1: out  A=attnb[8192][768], BT=woT[768][768] -> f32 Out +bias
template <int MODE>
__global__ __launch_bounds__(256) void k_gemm(
    const u16* __restrict__ A, const u16* __restrict__ BT,
    const float* __restrict__ bias0, const float* __restrict__ bias1,
    const float* __restrict__ bias2,
    u16* __restrict__ Qb, u16* __restrict__ Kb, u16* __restrict__ Vb,
    float* __restrict__ Out) {
  __shared__ __align__(16) u16 sg[16384];   // [buf][A:4096 | B:4096] u16
  const int m0 = blockIdx.x * 128, n0 = blockIdx.y * 128;
  const int t = threadIdx.x, w = t >> 6, lane = t & 63;
  const int g = lane >> 4, c = lane & 15;
  const int wr = w >> 1, wc = w & 1;

  const u16* ap[2]; const u16* bp[2]; int lo[2];
  #pragma unroll
  for (int ii = 0; ii < 2; ++ii) {
    int i = t + 256 * ii;
    ap[ii] = A + (size_t)(m0 + (i >> 2)) * 768 + (i & 3) * 8;
    bp[ii] = BT + (size_t)(n0 + (i >> 2)) * 768 + (i & 3) * 8;
    lo[ii] = (i & ~63) * 8;                 // wave-uniform u16 offset
  }
  auto STAGE = [&](int buf) {
    #pragma unroll
    for (int ii = 0; ii < 2; ++ii) {
      GLD16(ap[ii], &sg[buf * 4096 + lo[ii]]);
      GLD16(bp[ii], &sg[8192 + buf * 4096 + lo[ii]]);
      ap[ii] += 32; bp[ii] += 32;
    }
  };

  f32x4 acc[4][4] = {};
  STAGE(0);
  #pragma unroll 1
  for (int kk = 0; kk < 24; ++kk) {
    const int cur = kk & 1;
    if (kk < 23) { STAGE(cur ^ 1); VM_WAIT4(); } else { VM_WAIT0(); }
    BARRAW();
    u16x8 af[4], bf[4];
    #pragma unroll
    for (int mt = 0; mt < 4; ++mt)
      af[mt] = *(u16x8*)(&sg[cur * 4096 + (wr * 64 + mt * 16 + c) * 32 + g * 8]);
    #pragma unroll
    for (int nt = 0; nt < 4; ++nt)
      bf[nt] = *(u16x8*)(&sg[8192 + cur * 4096 + (wc * 64 + nt * 16 + c) * 32 + g * 8]);
    #pragma unroll
    for (int mt = 0; mt < 4; ++mt)
      #pragma unroll
      for (int nt = 0; nt < 4; ++nt)
        acc[mt][nt] = mfma16(af[mt], bf[nt], acc[mt][nt]);
    BARRAW();
  }

  // C layout per 16x16 tile: col = lane&15, row = (lane>>4)*4 + reg  [m89/m91]
  if (MODE == 0) {
    const int mat = n0 / 768;                       // never straddles
    const float* bias = (mat == 0) ? bias0 : (mat == 1) ? bias1 : bias2;
    u16* dst = (mat == 0) ? Qb : (mat == 1) ? Kb : Vb;
    const float qsc = (mat == 0) ? 1.44269504f : 1.0f;   // log2e into Q
    const int nbase = n0 - mat * 768;
    #pragma unroll
    for (int mt = 0; mt < 4; ++mt)
      #pragma unroll
      for (int nt = 0; nt < 4; ++nt) {
        int ncol = nbase + wc * 64 + nt * 16 + c;
        int h = ncol / 96, d = ncol % 96;           // 16-col run stays in one head
        float bi = bias[ncol];
        #pragma unroll
        for (int r = 0; r < 4; ++r) {
          int mrow = m0 + wr * 64 + mt * 16 + g * 4 + r;
          int b = mrow >> 12, ntok = mrow & 4095;
          dst[((size_t)((b * 8 + h) * 4096 + ntok)) * 96 + d] =
              f2h((acc[mt][nt][r] + bi) * qsc);
        }
      }
  } else {
    #pragma unroll
    for (int mt = 0; mt < 4; ++mt)
      #pragma unroll
      for (int nt = 0; nt < 4; ++nt) {
        int ncol = n0 + wc * 64 + nt * 16 + c;
        float bi = bias0[ncol];
        #pragma unroll
        for (int r = 0; r < 4; ++r) {
          int mrow = m0 + wr * 64 + mt * 16 + g * 4 + r;
          Out[(size_t)mrow * 768 + ncol] = acc[mt][nt][r] + bi;
        }
      }
  }
}

// ------------- flash attention: 4 waves x 32 q, deferred-PV, 1 barrier/tile -------------
// Energies in log2 units (Q pre-scaled). E^T = mfma(A=K, B=Q); lane owns q-col c
// for 2 q-blocks. Tile t: certify DMAs(t-1) via vmcnt(0), barrier, issue DMAs;
// energy(t); acc = acc*sc(t-1) + V(t-1)P(t-1) [pf in regs]; softmax(t); P pack.
__global__ __launch_bounds__(256) void k_attn(
    const u16* __restrict__ Q, const u16* __restrict__ K,
    const u16* __restrict__ Vt, u16* __restrict__ attn) {
  __shared__ __align__(16) u16 smem[34816];
  // [0,12288): K dbuf [2][64][96]; [12288,24576): V dbuf [2][96][64] swizzled;
  // [24576,34816): P [4 waves][2 qc][16][80]

  const int bid = blockIdx.x;
  const int bh = bid >> 5, qb = bid & 31;
  const int t = threadIdx.x, w = t >> 6, lane = t & 63;
  const int g = lane >> 4, c = lane & 15;
  const int q0 = qb * 128;

  // Q fragments (B-operand: lane holds Q[q = qc*16+c][d-chunk]); log2e pre-folded
  u16x8 qf[3][2];
  #pragma unroll
  for (int qc = 0; qc < 2; ++qc) {
    const size_t qoff = ((size_t)bh * 4096 + q0 + w * 32 + qc * 16 + c) * 96;
    #pragma unroll
    for (int kc = 0; kc < 3; ++kc)
      qf[kc][qc] = *(const u16x8*)(Q + qoff + kc * 32 + g * 8);
  }
  VM_WAIT0();   // drain Q loads so raw vmcnt counts below are clean

  const u16* Kbb = K + (size_t)bh * 4096 * 96;
  const u16* Vtb = Vt + (size_t)bh * 96 * 4096;
  const u16* ks[3]; const u16* vs[3]; int ko[3];
  #pragma unroll
  for (int ii = 0; ii < 3; ++ii) {
    int ci = t + 256 * ii;                  // 16B chunk id, 768 chunks per tile
    ks[ii] = Kbb + ci * 8;                  // K tile fully contiguous
    int d = ci >> 3, c8 = ci & 7;
    vs[ii] = Vtb + (size_t)d * 4096 + ((c8 ^ (d & 7)) * 8);  // pre-swizzled src
    ko[ii] = (ci & ~63) * 8;                // wave-uniform u16 offset
  }
  auto STAGE_K = [&](int buf) {
    #pragma unroll
    for (int ii = 0; ii < 3; ++ii) {
      GLD16(ks[ii], &smem[buf * 6144 + ko[ii]]);
      ks[ii] += 6144;                       // next KV tile (64 rows x 96)
    }
  };
  auto STAGE_V = [&](int buf) {
    #pragma unroll
    for (int ii = 0; ii < 3; ++ii) {
      GLD16(vs[ii], &smem[12288 + buf * 6144 + ko[ii]]);
      vs[ii] += 64;                         // next 64 kv columns
    }
  };

  f32x4 acc_o[6][2] = {};              // out^T[d = dt*16+g*4+r][q = qc*16+c]
  float m[2] = {-1e30f, -1e30f}, s[2] = {0.f, 0.f};
  float scp[2] = {1.f, 1.f};           // deferred rescale factors (tile t-1)
  bool flp[2] = {false, false};
  u16x8 pf[2][2];                      // P(t-1) fragments carried in registers
  u16* Pw = &smem[24576 + w * 2560];   // this wave's P region [2][16][80]

  STAGE_K(0);                          // prologue: K(0) -> buf0
  #pragma unroll 1
  for (int tt = 0; tt < 64; ++tt) {
    const int cur = tt & 1;
    VM_WAIT0();                        // certify this wave's DMAs issued at tt-1
    BARRAW();                          // publish cross-wave
    if (tt < 63) STAGE_K(cur ^ 1);     // K(tt+1)
    STAGE_V(cur);                      // V(tt)  (consumed at tt+1)

    // energy^T (log2 units): et[mt][qc] = E^T[k = mt*16+g*4+r][q = qc*16+c]
    const u16* Kl = &smem[cur * 6144];
    f32x4 et[4][2] = {};
    #pragma unroll
    for (int kc = 0; kc < 3; ++kc)
      #pragma unroll
      for (int mt = 0; mt < 4; ++mt) {
        u16x8 kf = *(const u16x8*)(&Kl[(mt * 16 + c) * 96 + kc * 32 + g * 8]);
        et[mt][0] = mfma16(kf, qf[kc][0], et[mt][0]);
        et[mt][1] = mfma16(kf, qf[kc][1], et[mt][1]);
      }

    // deferred: acc = acc*sc(t-1) + V(t-1)P(t-1)  (independent of et -> overlaps
    // with softmax below in the scheduler)
    if (tt > 0) {
      const u16* Vp = &smem[12288 + (cur ^ 1) * 6144];
      #pragma unroll
      for (int qc = 0; qc < 2; ++qc)
        if (flp[qc]) {
          #pragma unroll
          for (int dt = 0; dt < 6; ++dt)
            #pragma unroll
            for (int r = 0; r < 4; ++r) acc_o[dt][qc][r] *= scp[qc];
        }
      #pragma unroll
      for (int dt = 0; dt < 6; ++dt)
        #pragma unroll
        for (int kb = 0; kb < 2; ++kb) {
          u16x8 vf = *(const u16x8*)(&Vp[(dt * 16 + c) * 64 +
                                         (((kb * 4 + g) ^ (c & 7)) * 8)]);
          acc_o[dt][0] = mfma16(vf, pf[0][kb], acc_o[dt][0]);
          acc_o[dt][1] = mfma16(vf, pf[1][kb], acc_o[dt][1]);
        }
    }

    // online softmax, log2 domain, defer-max (THR=12 -> P <= 4096, fp16-safe)
    #pragma unroll
    for (int qc = 0; qc < 2; ++qc) {
      float t0 = fmaxf(fmaxf(et[0][qc][0], et[0][qc][1]),
                       fmaxf(et[0][qc][2], et[0][qc][3]));
      float t1 = fmaxf(fmaxf(et[1][qc][0], et[1][qc][1]),
                       fmaxf(et[1][qc][2], et[1][qc][3]));
      float t2 = fmaxf(fmaxf(et[2][qc][0], et[2][qc][1]),
                       fmaxf(et[2][qc][2], et[2][qc][3]));
      float t3 = fmaxf(fmaxf(et[3][qc][0], et[3][qc][1]),
                       fmaxf(et[3][qc][2], et[3][qc][3]));
      float tmax = fmaxf(fmaxf(t0, t1), fmaxf(t2, t3));
      tmax = fmaxf(tmax, __shfl_xor(tmax, 16));
      tmax = fmaxf(tmax, __shfl_xor(tmax, 32));
      bool upd = tmax > m[qc] + 12.0f;
      float mnew = upd ? tmax : m[qc];
      float sct = exp2fast(m[qc] - mnew);   // ==1 when !upd
      m[qc] = mnew;
      float psum = 0.f;
      #pragma unroll
      for (int mt = 0; mt < 4; ++mt)
        #pragma unroll
        for (int r = 0; r < 4; ++r) {
          float p = exp2fast(et[mt][qc][r] - mnew);
          et[mt][qc][r] = p; psum += p;
        }
      psum += __shfl_xor(psum, 16);
      psum += __shfl_xor(psum, 32);
      s[qc] = s[qc] * sct + psum;           // s tracks m(t) immediately
      scp[qc] = sct;                        // acc rescale deferred to t+1
      flp[qc] = __any(upd);

      // P (fp16, RTZ pack) -> per-wave per-qc LDS [16 q][64 k]
      u16* P = Pw + qc * 1280;
      #pragma unroll
      for (int mt = 0; mt < 4; ++mt) {
        unsigned p0 = pkrtz(et[mt][qc][0], et[mt][qc][1]);
        unsigned p1 = pkrtz(et[mt][qc][2], et[mt][qc][3]);
        *(u64*)(&P[c * 80 + mt * 16 + g * 4]) = (u64)p0 | ((u64)p1 << 32);
      }
    }
    // read back P(t) fragments for next tile's PV: lane holds P[k=kb*32+g*8+j][q]
    #pragma unroll
    for (int qc = 0; qc < 2; ++qc)
      #pragma unroll
      for (int kb = 0; kb < 2; ++kb)
        pf[qc][kb] = *(u16x8*)(&Pw[qc * 1280 + c * 80 + kb * 32 + g * 8]);
  }

  // tail: finish tile 63's PV
  VM_WAIT0();
  BARRAW();
  {
    const u16* Vp = &smem[12288 + 1 * 6144];   // V(63) in buf 1
    #pragma unroll
    for (int qc = 0; qc < 2; ++qc)
      if (flp[qc]) {
        #pragma unroll
        for (int dt = 0; dt < 6; ++dt)
          #pragma unroll
          for (int r = 0; r < 4; ++r) acc_o[dt][qc][r] *= scp[qc];
      }
    #pragma unroll
    for (int dt = 0; dt < 6; ++dt)
      #pragma unroll
      for (int kb = 0; kb < 2; ++kb) {
        u16x8 vf = *(const u16x8*)(&Vp[(dt * 16 + c) * 64 +
                                       (((kb * 4 + g) ^ (c & 7)) * 8)]);
        acc_o[dt][0] = mfma16(vf, pf[0][kb], acc_o[dt][0]);
        acc_o[dt][1] = mfma16(vf, pf[1][kb], acc_o[dt][1]);
      }
  }

  // reference: att = softmax(E)/sqrt(D)  ->  out = (O/s)/sqrt(96)
  __syncthreads();
  u16* O = smem;  // reuse as [128 q][96 d]
  #pragma unroll
  for (int qc = 0; qc < 2; ++qc) {
    const float inv = 1.0f / (s[qc] * 9.797958971132712f);
    #pragma unroll
    for (int dt = 0; dt < 6; ++dt)
      #pragma unroll
      for (int rp = 0; rp < 2; ++rp) {
        unsigned pk = (unsigned)f2h(acc_o[dt][qc][2 * rp] * inv) |
                      ((unsigned)f2h(acc_o[dt][qc][2 * rp + 1] * inv) << 16);
        *(unsigned*)(&O[(w * 32 + qc * 16 + c) * 96 + dt * 16 + g * 4 + 2 * rp]) = pk;
      }
  }
  __syncthreads();
  const int b = bh >> 3, h = bh & 7;
  #pragma unroll
  for (int ii = 0; ii < 6; ++ii) {
    int i = t + 256 * ii, r = i / 12, c8 = i % 12;
    u16x8 v = *(u16x8*)(&O[r * 96 + c8 * 8]);
    *(u16x8*)(attn + ((size_t)(b * 4096 + q0 + r)) * 768 + h * 96 + c8 * 8) = v;
  }
}

// ---------------------------------------------------------------------
extern "C" void kernel_launch(void* const* d_in, const int* in_sizes, int n_in,
                              void* d_out, int out_size, void* d_ws, size_t ws_size,
                              hipStream_t stream) {
  const float* x  = (const float*)d_in[0];
  const float* Wq = (const float*)d_in[1];
  const float* bq = (const float*)d_in[2];
  const float* Wk = (const float*)d_in[3];
  const float* bk = (const float*)d_in[4];
  const float* Wv = (const float*)d_in[5];
  const float* bv = (const float*)d_in[6];
  const float* Wo = (const float*)d_in[7];
  const float* bo = (const float*)d_in[8];
  float* out = (float*)d_out;

  char* ws = (char*)d_ws;
  size_t off = 0;
  auto alloc = [&](size_t bytes) {
    void* p = ws + off;
    off += (bytes + 1023) & ~(size_t)1023;
    return p;
  };
  const size_t SZ = (size_t)16 * 4096 * 96 * 2;      // 12.6 MB per [B,H,N,D] fp16
  u16* xh    = (u16*)alloc((size_t)8192 * 768 * 2);
  u16* wT    = (u16*)alloc((size_t)4 * 768 * 768 * 2);
  u16* Qb    = (u16*)alloc(SZ);
  u16* Kb    = (u16*)alloc(SZ);
  u16* Vb    = (u16*)alloc(SZ);
  u16* Vtb   = (u16*)alloc(SZ);
  u16* attnb = (u16*)alloc(SZ);
  (void)ws_size; (void)in_sizes; (void)n_in; (void)out_size;

  k_cast<<<3072, 256, 0, stream>>>(x, xh, 786432);
  k_wt<<<576, 256, 0, stream>>>(Wq, Wk, Wv, Wo, wT);
  k_gemm<0><<<dim3(64, 18), 256, 0, stream>>>(xh, wT, bq, bk, bv,
                                              Qb, Kb, Vb, nullptr);
  k_vt<<<1024, 256, 0, stream>>>(Vb, Vtb);
  k_attn<<<512, 256, 0, stream>>>(Qb, Kb, Vtb, attnb);
  k_gemm<1><<<dim3(64, 6), 256, 0, stream>>>(attnb, wT + (size_t)3 * 589824,
                                             bo, nullptr, nullptr,
                                             nullptr, nullptr, nullptr, out);
}